// Round 11
// baseline (587.839 us; speedup 1.0000x reference)
//
#include <hip/hip_runtime.h>
#include <stdint.h>

// Periodic radius-graph neighbor list (AlphaNet). B=16, N=256, C=27, M=6912.
// R11 = MEASUREMENT: R10 two-phase structure, sweep launched TWICE (idempotent)
// to isolate sweep time: S = dur_R11 - dur_R10 (+small edges delta). Edges
// leaned out: rank scan writes kws directly (no kept[] LDS round-trip).

constexpr int B_ = 16, N_ = 256, C_ = 27;
constexpr int M_ = N_ * C_;            // 6912
constexpr int MAXC = 256;
constexpr int KMAX = 32;
constexpr int NR   = B_ * N_;          // 4096 receivers
constexpr int DGPR = M_ / 4;           // 1728 dist groups per receiver
constexpr int VG   = 3 * M_ / 4;       // 5184 dvec groups per receiver
constexpr int DG = NR * DGPR;          // dist groups total
constexpr int NG = DG + NR * VG;       // all float4 groups
constexpr int SWEEP_BLOCKS = 2048;

typedef float vfloat4 __attribute__((ext_vector_type(4)));

__device__ __forceinline__ void nt_store4(float* p, float a, float b, float c, float d) {
    vfloat4 v; v.x = a; v.y = b; v.z = c; v.w = d;
    __builtin_nontemporal_store(v, (vfloat4*)p);
}

__global__ __launch_bounds__(256)
void edges_kernel(const float* __restrict__ pos,    // [B,N,3]
                  const float* __restrict__ cell,   // [B,3,3]
                  float* __restrict__ nn,           // [B] (pre-zeroed)
                  uint32_t* __restrict__ sws,       // [NR * DGPR] slot words
                  float4*  __restrict__ kws)        // [NR * KMAX] dx,dy,dz,dist
{
#pragma clang fp contract(off)
    __shared__ float offx[C_], offy[C_], offz[C_];
    __shared__ unsigned long long keys[MAXC];
    __shared__ float4 vals[MAXC];
    __shared__ unsigned char slot[M_];
    __shared__ int cnt;

    const int bi  = blockIdx.x;
    const int b   = bi >> 8;
    const int i   = bi & 255;
    const int tid = threadIdx.x;

    const float* pb = pos + b * N_ * 3;
    const float pjx = pb[tid * 3 + 0], pjy = pb[tid * 3 + 1], pjz = pb[tid * 3 + 2];
    const float pix = pb[i * 3 + 0],   piy = pb[i * 3 + 1],   piz = pb[i * 3 + 2];

    if (tid < C_) {
        const float n1 = (float)(tid / 9 - 1);
        const float n2 = (float)((tid / 3) % 3 - 1);
        const float n3 = (float)(tid % 3 - 1);
        const float* cb = cell + b * 9;
        offx[tid] = n1 * cb[0] + n2 * cb[3] + n3 * cb[6];
        offy[tid] = n1 * cb[1] + n2 * cb[4] + n3 * cb[7];
        offz[tid] = n1 * cb[2] + n2 * cb[5] + n3 * cb[8];
    }
    uint32_t* slot32 = (uint32_t*)slot;
    for (int w = tid; w < DGPR; w += 256) slot32[w] = 0;
    if (tid == 0) cnt = 0;
    __syncthreads();

    // bit-exact numpy order: s = pj + off; d = pi - s; ((dx*dx+dy*dy)+dz*dz)
    #pragma unroll 1
    for (int c = 0; c < C_; ++c) {
        const float sx = pjx + offx[c], sy = pjy + offy[c], sz = pjz + offz[c];
        const float dx = pix - sx, dy = piy - sy, dz = piz - sz;
        const float dsq = dx * dx + dy * dy + dz * dz;
        if (dsq <= 25.0f && dsq > 1e-4f) {
            const int idx = atomicAdd(&cnt, 1);
            if (idx < MAXC) {
                keys[idx] = ((unsigned long long)__float_as_uint(dsq) << 32)
                          | (unsigned)(tid * C_ + c);
                vals[idx] = make_float4(dx, dy, dz, dsq);
            }
        }
    }
    __syncthreads();

    int K = cnt; if (K > MAXC) K = MAXC;
    if (tid == 0)
        atomicAdd(&nn[b], (float)(K < KMAX ? K : KMAX));

    // rank scan -> kws written directly (no kept[] LDS round-trip)
    for (int idx = tid; idx < K; idx += 256) {
        const unsigned long long key = keys[idx];
        int r = 0;
        for (int q = 0; q < K; ++q) r += (keys[q] < key) ? 1 : 0;
        if (r < KMAX) {
            const int m = (int)(key & 0xffffffffu);
            const float4 v = vals[idx];
            kws[bi * KMAX + r] = make_float4(v.x, v.y, v.z, sqrtf(v.w));
            slot[m] = (unsigned char)(r + 1);
        }
    }
    __syncthreads();

    uint32_t* sw = sws + (size_t)bi * DGPR;
    for (int w = tid; w < DGPR; w += 256) sw[w] = slot32[w];
}

__global__ __launch_bounds__(256)
void sweep_kernel(const uint32_t* __restrict__ sws,  // [NR * DGPR]
                  const float4*  __restrict__ kws,   // [NR * KMAX]
                  float* __restrict__ out)           // dist||dvec, NG float4 groups
{
    const int stride = SWEEP_BLOCKS * 256;
    for (int g = blockIdx.x * 256 + threadIdx.x; g < NG; g += stride) {
        float o0 = 0.f, o1 = 0.f, o2 = 0.f, o3 = 0.f;
        if (g < DG) {
            const uint32_t s4 = sws[g];
            if (s4) {
                const int bi = g / DGPR;
                const float4* kb = kws + bi * KMAX;
                uint32_t s;
                s = s4 & 0xffu;         if (s) o0 = kb[s - 1].w;
                s = (s4 >> 8) & 0xffu;  if (s) o1 = kb[s - 1].w;
                s = (s4 >> 16) & 0xffu; if (s) o2 = kb[s - 1].w;
                s = (s4 >> 24) & 0xffu; if (s) o3 = kb[s - 1].w;
            }
        } else {
            const int h  = g - DG;
            const int bi = h / VG;
            const int hh = h - bi * VG;
            const int e0 = 4 * hh;
            const int m0 = e0 / 3;
            const int m1 = (e0 + 3) / 3;
            const unsigned char* sb = (const unsigned char*)sws + (size_t)bi * M_;
            const uint32_t sA = sb[m0], sB = sb[m1];
            if ((sA | sB) != 0) {
                const float4* kb = kws + bi * KMAX;
                float o[4] = {0.f, 0.f, 0.f, 0.f};
                #pragma unroll
                for (int u = 0; u < 4; ++u) {
                    const int e = e0 + u;
                    const int m = e / 3;
                    const int d = e - 3 * m;
                    const uint32_t s = (m == m0) ? sA : sB;
                    if (s) o[u] = (&kb[s - 1].x)[d];
                }
                o0 = o[0]; o1 = o[1]; o2 = o[2]; o3 = o[3];
            }
        }
        nt_store4(out + 4 * (size_t)g, o0, o1, o2, o3);
    }
}

extern "C" void kernel_launch(void* const* d_in, const int* in_sizes, int n_in,
                              void* d_out, int out_size, void* d_ws, size_t ws_size,
                              hipStream_t stream)
{
    const float* pos  = (const float*)d_in[0];
    const float* cell = (const float*)d_in[1];
    float* out = (float*)d_out;                       // dist || dvec || nn
    float* nn  = out + (size_t)NR * M_ * 4;

    uint32_t* sws = (uint32_t*)d_ws;                  // 28.3 MB
    float4*   kws = (float4*)((char*)d_ws + (size_t)NR * DGPR * 4);  // 2 MB

    (void)hipMemsetAsync(nn, 0, B_ * sizeof(float), stream);
    edges_kernel<<<dim3(NR), dim3(256), 0, stream>>>(pos, cell, nn, sws, kws);
    // sweep twice: second run overwrites identically; isolates S = dur_R11 - dur_R10
    sweep_kernel<<<dim3(SWEEP_BLOCKS), dim3(256), 0, stream>>>(sws, kws, out);
    sweep_kernel<<<dim3(SWEEP_BLOCKS), dim3(256), 0, stream>>>(sws, kws, out);
}

// Round 12
// 519.067 us; speedup vs baseline: 1.1325x; 1.1325x over previous
//
#include <hip/hip_runtime.h>
#include <stdint.h>

// Periodic radius-graph neighbor list (AlphaNet). B=16, N=256, C=27, M=6912.
// Outputs (flat f32 concat): dist [B,N,M], dvec [B,N,M,3], num_neighbors_image [B].
// keep = (1e-4 < dsqr <= 25) AND stable-sort rank < 32
//      == key (f32bits(dsqr)<<32 | m) among the 32 smallest within-radius keys.
//
// R12: wave-per-receiver edges (no LDS atomics, no phase barriers, ballot
// compaction; 4096 waves all resident) + R11's proven lockstep sweep
// (82 us @ ~6 TB/s: contiguous sliding window == rocclr fill shape).
// Measured: fused plateau 4.3 TB/s (page thrash from 2048 block streams);
// R10/R11 isolated edges = 62 us (block-barrier/latency bound) -> redesigned.

constexpr int B_ = 16, N_ = 256, C_ = 27;
constexpr int M_ = N_ * C_;            // 6912
constexpr int MAXC = 160;              // per-wave candidate slots (mean 78, +9.3 sigma)
constexpr int KMAX = 32;
constexpr int NR   = B_ * N_;          // 4096 receivers
constexpr int WPB  = 4;                // waves (receivers) per block
constexpr int DGPR = M_ / 4;           // 1728 slot words per receiver
constexpr int VG   = 3 * M_ / 4;       // 5184 dvec groups per receiver
constexpr int DG = NR * DGPR;
constexpr int NG = DG + NR * VG;
constexpr int SWEEP_BLOCKS = 2048;

typedef float vfloat4 __attribute__((ext_vector_type(4)));

__device__ __forceinline__ void nt_store4(float* p, float a, float b, float c, float d) {
    vfloat4 v; v.x = a; v.y = b; v.z = c; v.w = d;
    __builtin_nontemporal_store(v, (vfloat4*)p);
}

__global__ __launch_bounds__(256)
void edges_kernel(const float* __restrict__ pos,    // [B,N,3]
                  const float* __restrict__ cell,   // [B,3,3]
                  float* __restrict__ nn,           // [B] (pre-zeroed)
                  uint32_t* __restrict__ sws,       // [NR * DGPR] slot words
                  float4*  __restrict__ kws)        // [NR * KMAX] dx,dy,dz,dist
{
#pragma clang fp contract(off)
    __shared__ float offx[C_], offy[C_], offz[C_];
    __shared__ unsigned long long keys[WPB][MAXC];
    __shared__ __align__(16) unsigned char slot[WPB][M_];

    const int tid  = threadIdx.x;
    const int w    = tid >> 6;           // wave 0..3
    const int lane = tid & 63;
    const int bi   = blockIdx.x * WPB + w;   // receiver (same b for all 4 waves)
    const int b    = bi >> 8;
    const int i    = bi & 255;

    const float* pb = pos + b * N_ * 3;

    if (tid < C_) {                      // b is block-uniform
        const float n1 = (float)(tid / 9 - 1);
        const float n2 = (float)((tid / 3) % 3 - 1);
        const float n3 = (float)(tid % 3 - 1);
        const float* cb = cell + b * 9;
        offx[tid] = n1 * cb[0] + n2 * cb[3] + n3 * cb[6];
        offy[tid] = n1 * cb[1] + n2 * cb[4] + n3 * cb[7];
        offz[tid] = n1 * cb[2] + n2 * cb[5] + n3 * cb[8];
    }
    // zero this wave's slot bytes (wave-private, no barrier needed)
    {
        uint4* s4 = (uint4*)slot[w];
        const uint4 z = make_uint4(0u, 0u, 0u, 0u);
        for (int k = lane; k < M_ / 16; k += 64) s4[k] = z;
    }
    __syncthreads();                     // offs ready

    const float pix = pb[i * 3 + 0], piy = pb[i * 3 + 1], piz = pb[i * 3 + 2];

    // pass 1: lane owns j = jj*64+lane; lockstep ballot compaction, no atomics.
    // bit-exact numpy order: s = pj + off; d = pi - s; ((dx*dx+dy*dy)+dz*dz)
    int wbase = 0;
    #pragma unroll 1
    for (int jj = 0; jj < 4; ++jj) {
        const int j = jj * 64 + lane;
        const float pjx = pb[j * 3 + 0], pjy = pb[j * 3 + 1], pjz = pb[j * 3 + 2];
        #pragma unroll 1
        for (int c = 0; c < C_; ++c) {
            const float sx = pjx + offx[c], sy = pjy + offy[c], sz = pjz + offz[c];
            const float dx = pix - sx, dy = piy - sy, dz = piz - sz;
            const float dsq = dx * dx + dy * dy + dz * dz;
            const bool within = (dsq <= 25.0f) && (dsq > 1e-4f);
            const unsigned long long mask = __ballot(within);
            if (within) {
                const int p = __popcll(mask & ((1ull << lane) - 1ull));
                const int s = wbase + p;
                if (s < MAXC)
                    keys[w][s] = ((unsigned long long)__float_as_uint(dsq) << 32)
                               | (unsigned)(j * C_ + c);
            }
            wbase += __popcll(mask);     // wave-uniform
        }
    }
    int K = (wbase > MAXC) ? MAXC : wbase;
    const int kept = (K < KMAX) ? K : KMAX;
    if (lane == 0)
        atomicAdd(&nn[b], (float)kept);  // 4096 adds over 16 addrs (proven cheap)

    // rank scan (keys unique) + export winners with bit-exact recompute
    for (int idx = lane; idx < K; idx += 64) {
        const unsigned long long key = keys[w][idx];
        int r = 0;
        for (int q = 0; q < K; ++q) r += (keys[w][q] < key) ? 1 : 0;
        if (r < KMAX) {
            const int m = (int)(key & 0xffffffffu);
            slot[w][m] = (unsigned char)(r + 1);
            const int j = m / C_;
            const int c = m - j * C_;
            const float sx = pb[j * 3 + 0] + offx[c];
            const float sy = pb[j * 3 + 1] + offy[c];
            const float sz = pb[j * 3 + 2] + offz[c];
            const float dx = pix - sx, dy = piy - sy, dz = piz - sz;
            const float dsq = dx * dx + dy * dy + dz * dz;
            kws[bi * KMAX + r] = make_float4(dx, dy, dz, sqrtf(dsq));
        }
    }
    __syncthreads();                     // order scattered slot writes before export

    // export this wave's slot words, coalesced 16B
    {
        uint4* sw = (uint4*)(sws + (size_t)bi * DGPR);   // 432 uint4 per receiver
        const uint4* sl = (const uint4*)slot[w];
        for (int k = lane; k < DGPR / 4; k += 64) sw[k] = sl[k];
    }
}

__global__ __launch_bounds__(256)
void sweep_kernel(const uint32_t* __restrict__ sws,  // [NR * DGPR]
                  const float4*  __restrict__ kws,   // [NR * KMAX]
                  float* __restrict__ out)           // dist||dvec, NG float4 groups
{
    const int stride = SWEEP_BLOCKS * 256;
    for (int g = blockIdx.x * 256 + threadIdx.x; g < NG; g += stride) {
        float o0 = 0.f, o1 = 0.f, o2 = 0.f, o3 = 0.f;
        if (g < DG) {
            const uint32_t s4 = sws[g];
            if (s4) {
                const int bi = g / DGPR;
                const float4* kb = kws + bi * KMAX;
                uint32_t s;
                s = s4 & 0xffu;         if (s) o0 = kb[s - 1].w;
                s = (s4 >> 8) & 0xffu;  if (s) o1 = kb[s - 1].w;
                s = (s4 >> 16) & 0xffu; if (s) o2 = kb[s - 1].w;
                s = (s4 >> 24) & 0xffu; if (s) o3 = kb[s - 1].w;
            }
        } else {
            const int h  = g - DG;
            const int bi = h / VG;
            const int hh = h - bi * VG;
            const int e0 = 4 * hh;
            const int m0 = e0 / 3;
            const int m1 = (e0 + 3) / 3;
            const unsigned char* sb = (const unsigned char*)sws + (size_t)bi * M_;
            const uint32_t sA = sb[m0], sB = sb[m1];
            if ((sA | sB) != 0) {
                const float4* kb = kws + bi * KMAX;
                float o[4] = {0.f, 0.f, 0.f, 0.f};
                #pragma unroll
                for (int u = 0; u < 4; ++u) {
                    const int e = e0 + u;
                    const int m = e / 3;
                    const int d = e - 3 * m;
                    const uint32_t s = (m == m0) ? sA : sB;
                    if (s) o[u] = (&kb[s - 1].x)[d];
                }
                o0 = o[0]; o1 = o[1]; o2 = o[2]; o3 = o[3];
            }
        }
        nt_store4(out + 4 * (size_t)g, o0, o1, o2, o3);
    }
}

extern "C" void kernel_launch(void* const* d_in, const int* in_sizes, int n_in,
                              void* d_out, int out_size, void* d_ws, size_t ws_size,
                              hipStream_t stream)
{
    const float* pos  = (const float*)d_in[0];
    const float* cell = (const float*)d_in[1];
    float* out = (float*)d_out;                       // dist || dvec || nn
    float* nn  = out + (size_t)NR * M_ * 4;

    uint32_t* sws = (uint32_t*)d_ws;                  // 28.3 MB
    float4*   kws = (float4*)((char*)d_ws + (size_t)NR * DGPR * 4);  // 2 MB

    (void)hipMemsetAsync(nn, 0, B_ * sizeof(float), stream);
    edges_kernel<<<dim3(NR / WPB), dim3(256), 0, stream>>>(pos, cell, nn, sws, kws);
    sweep_kernel<<<dim3(SWEEP_BLOCKS), dim3(256), 0, stream>>>(sws, kws, out);
}

// Round 13
// 467.150 us; speedup vs baseline: 1.2584x; 1.1111x over previous
//
#include <hip/hip_runtime.h>
#include <stdint.h>

// Periodic radius-graph neighbor list (AlphaNet). B=16, N=256, C=27, M=6912.
// Outputs (flat f32 concat): dist [B,N,M], dvec [B,N,M,3], num_neighbors_image [B].
// keep = (1e-4 < dsqr <= 25) AND stable-sort rank < 32
//      == key (f32bits(dsqr)<<32 | m) among the 32 smallest within-radius keys.
//
// R13: ZERO global atomics. Edges (block-per-receiver, lean): candidates ->
// rank scan -> slot bytes + kept table + ecnt[bi] plain store. Sweep (lockstep
// sliding window, proven 82 us @ 6 TB/s) writes dist||dvec; its block 0 also
// reduces ecnt -> nn (16 sums of 256 ints). Theory: the stable 62-75 us edges
// cost across 3 rewrites was 4096 same-line device-scope atomicAdds on nn[16].

constexpr int B_ = 16, N_ = 256, C_ = 27;
constexpr int M_ = N_ * C_;            // 6912
constexpr int MAXC = 256;              // LDS candidate slots; mean ~78
constexpr int KMAX = 32;
constexpr int NR   = B_ * N_;          // 4096 receivers
constexpr int DGPR = M_ / 4;           // 1728 slot words per receiver
constexpr int VG   = 3 * M_ / 4;       // 5184 dvec groups per receiver
constexpr int DG = NR * DGPR;
constexpr int NG = DG + NR * VG;       // 28,311,552 float4 groups = dist||dvec
constexpr int SWEEP_BLOCKS = 2048;

typedef float vfloat4 __attribute__((ext_vector_type(4)));

__device__ __forceinline__ void nt_store4(float* p, float a, float b, float c, float d) {
    vfloat4 v; v.x = a; v.y = b; v.z = c; v.w = d;
    __builtin_nontemporal_store(v, (vfloat4*)p);
}

__global__ __launch_bounds__(256)
void edges_kernel(const float* __restrict__ pos,    // [B,N,3]
                  const float* __restrict__ cell,   // [B,3,3]
                  int*   __restrict__ ecnt,         // [NR] kept count (plain store)
                  uint32_t* __restrict__ sws,       // [NR * DGPR] slot words
                  float4*  __restrict__ kws)        // [NR * KMAX] dx,dy,dz,dist
{
#pragma clang fp contract(off)
    __shared__ float offx[C_], offy[C_], offz[C_];
    __shared__ unsigned long long keys[MAXC];
    __shared__ __align__(16) unsigned char slot[M_];
    __shared__ int cnt;

    const int bi  = blockIdx.x;
    const int b   = bi >> 8;
    const int i   = bi & 255;
    const int tid = threadIdx.x;

    const float* pb = pos + b * N_ * 3;
    const float pjx = pb[tid * 3 + 0], pjy = pb[tid * 3 + 1], pjz = pb[tid * 3 + 2];
    const float pix = pb[i * 3 + 0],   piy = pb[i * 3 + 1],   piz = pb[i * 3 + 2];

    if (tid < C_) {
        const float n1 = (float)(tid / 9 - 1);
        const float n2 = (float)((tid / 3) % 3 - 1);
        const float n3 = (float)(tid % 3 - 1);
        const float* cb = cell + b * 9;
        offx[tid] = n1 * cb[0] + n2 * cb[3] + n3 * cb[6];
        offy[tid] = n1 * cb[1] + n2 * cb[4] + n3 * cb[7];
        offz[tid] = n1 * cb[2] + n2 * cb[5] + n3 * cb[8];
    }
    {
        uint4* s4 = (uint4*)slot;
        const uint4 z = make_uint4(0u, 0u, 0u, 0u);
        for (int k = tid; k < M_ / 16; k += 256) s4[k] = z;
    }
    if (tid == 0) cnt = 0;
    __syncthreads();

    // pass 1: bit-exact numpy order: s = pj + off; d = pi - s; ((dx*dx+dy*dy)+dz*dz)
    #pragma unroll 1
    for (int c = 0; c < C_; ++c) {
        const float sx = pjx + offx[c], sy = pjy + offy[c], sz = pjz + offz[c];
        const float dx = pix - sx, dy = piy - sy, dz = piz - sz;
        const float dsq = dx * dx + dy * dy + dz * dz;
        if (dsq <= 25.0f && dsq > 1e-4f) {
            const int idx = atomicAdd(&cnt, 1);              // LDS atomic only
            if (idx < MAXC)
                keys[idx] = ((unsigned long long)__float_as_uint(dsq) << 32)
                          | (unsigned)(tid * C_ + c);
        }
    }
    __syncthreads();

    int K = cnt; if (K > MAXC) K = MAXC;
    if (tid == 0)
        ecnt[bi] = (K < KMAX) ? K : KMAX;                    // plain store, no atomic

    // rank scan (keys unique) + export winners (bit-exact recompute of d-vector)
    for (int idx = tid; idx < K; idx += 256) {
        const unsigned long long key = keys[idx];
        int r = 0;
        for (int q = 0; q < K; ++q) r += (keys[q] < key) ? 1 : 0;
        if (r < KMAX) {
            const int m = (int)(key & 0xffffffffu);
            slot[m] = (unsigned char)(r + 1);
            const int j = m / C_;
            const int c = m - j * C_;
            const float sx = pb[j * 3 + 0] + offx[c];
            const float sy = pb[j * 3 + 1] + offy[c];
            const float sz = pb[j * 3 + 2] + offz[c];
            const float dx = pix - sx, dy = piy - sy, dz = piz - sz;
            const float dsq = dx * dx + dy * dy + dz * dz;
            kws[bi * KMAX + r] = make_float4(dx, dy, dz, sqrtf(dsq));
        }
    }
    __syncthreads();

    // export slot words, coalesced 16B
    {
        uint4* sw = (uint4*)(sws + (size_t)bi * DGPR);       // 432 uint4
        const uint4* sl = (const uint4*)slot;
        for (int k = tid; k < DGPR / 4; k += 256) sw[k] = sl[k];
    }
}

__global__ __launch_bounds__(256)
void sweep_kernel(const uint32_t* __restrict__ sws,  // [NR * DGPR]
                  const float4*  __restrict__ kws,   // [NR * KMAX]
                  const int*     __restrict__ ecnt,  // [NR]
                  float* __restrict__ out,           // dist||dvec, NG float4 groups
                  float* __restrict__ nn)            // [B]
{
    // nn reduction: block 0, lanes 0..15 each sum 256 contiguous ints
    if (blockIdx.x == 0 && threadIdx.x < B_) {
        const int* e = ecnt + threadIdx.x * N_;
        int s = 0;
        for (int k = 0; k < N_; ++k) s += e[k];
        nn[threadIdx.x] = (float)s;
    }

    const int stride = SWEEP_BLOCKS * 256;
    for (int g = blockIdx.x * 256 + threadIdx.x; g < NG; g += stride) {
        float o0 = 0.f, o1 = 0.f, o2 = 0.f, o3 = 0.f;
        if (g < DG) {
            const uint32_t s4 = sws[g];
            if (s4) {
                const int bi = g / DGPR;
                const float4* kb = kws + bi * KMAX;
                uint32_t s;
                s = s4 & 0xffu;         if (s) o0 = kb[s - 1].w;
                s = (s4 >> 8) & 0xffu;  if (s) o1 = kb[s - 1].w;
                s = (s4 >> 16) & 0xffu; if (s) o2 = kb[s - 1].w;
                s = (s4 >> 24) & 0xffu; if (s) o3 = kb[s - 1].w;
            }
        } else {
            const int h  = g - DG;
            const int bi = h / VG;
            const int hh = h - bi * VG;
            const int e0 = 4 * hh;
            const int m0 = e0 / 3;
            const int m1 = (e0 + 3) / 3;
            const unsigned char* sb = (const unsigned char*)sws + (size_t)bi * M_;
            const uint32_t sA = sb[m0], sB = sb[m1];
            if ((sA | sB) != 0) {
                const float4* kb = kws + bi * KMAX;
                float o[4] = {0.f, 0.f, 0.f, 0.f};
                #pragma unroll
                for (int u = 0; u < 4; ++u) {
                    const int e = e0 + u;
                    const int m = e / 3;
                    const int d = e - 3 * m;
                    const uint32_t s = (m == m0) ? sA : sB;
                    if (s) o[u] = (&kb[s - 1].x)[d];
                }
                o0 = o[0]; o1 = o[1]; o2 = o[2]; o3 = o[3];
            }
        }
        nt_store4(out + 4 * (size_t)g, o0, o1, o2, o3);
    }
}

extern "C" void kernel_launch(void* const* d_in, const int* in_sizes, int n_in,
                              void* d_out, int out_size, void* d_ws, size_t ws_size,
                              hipStream_t stream)
{
    const float* pos  = (const float*)d_in[0];
    const float* cell = (const float*)d_in[1];
    float* out = (float*)d_out;                       // dist || dvec || nn
    float* nn  = out + (size_t)NR * M_ * 4;

    uint32_t* sws = (uint32_t*)d_ws;                                  // 28.3 MB
    float4*   kws = (float4*)((char*)d_ws + (size_t)NR * DGPR * 4);   // 2 MB
    int*      ecnt = (int*)((char*)d_ws + (size_t)NR * DGPR * 4 + (size_t)NR * KMAX * 16);

    edges_kernel<<<dim3(NR), dim3(256), 0, stream>>>(pos, cell, ecnt, sws, kws);
    sweep_kernel<<<dim3(SWEEP_BLOCKS), dim3(256), 0, stream>>>(sws, kws, ecnt, out, nn);
}